// Round 14
// baseline (343.194 us; speedup 1.0000x reference)
//
#include <hip/hip_runtime.h>
#include <hip/hip_bf16.h>
#include <math.h>

#define LMAX 360
#define MMAX 361
#define NLAT 361
#define NLON 720
#define BC   32
#define MT   (BC*2*NLAT)   // 23104 rows
#define QT   722           // valid K (2*MMAX) for stage-2 GEMM
#define KP   736           // stage-2 padded K = 23*32
#define NP   768           // stage-2 padded N
#define BM   128
#define BN   128
#define BK   32

typedef __attribute__((ext_vector_type(8))) short short8;
typedef __attribute__((ext_vector_type(4))) float f32x4;

static __device__ __forceinline__ short f2bf(float v) {
    __hip_bfloat16 h = __float2bfloat16(v);
    return *reinterpret_cast<short*>(&h);
}

// ---------------------------------------------------------------------------
// prep_x (unchanged, proven): x fp32 [bc][f][l][m][ri] -> xT bf16
// [m][src*32+bc][l], src = f*2 + ri, rows 360 bf16 = 720 B.
// ---------------------------------------------------------------------------
__global__ __launch_bounds__(256) void sht_prep_x(
    const float* __restrict__ x, __hip_bfloat16* __restrict__ xT)
{
    const int m0 = blockIdx.x * 32;
    const int l0 = blockIdx.y * 64;
    const int bc = blockIdx.z >> 1, f = blockIdx.z & 1;
    __shared__ float2 tile[64][33];
    const float2* __restrict__ x2 = (const float2*)x;
    const int t = threadIdx.x;
    const int rm = t & 31, rl = t >> 5;

    const int mm = min(m0 + rm, MMAX - 1);
    #pragma unroll
    for (int r = 0; r < 8; ++r) {
        int l = min(l0 + rl + r * 8, LMAX - 1);
        tile[rl + r * 8][rm] = x2[((size_t)(bc * 2 + f) * LMAX + l) * MMAX + mm];
    }
    __syncthreads();

    const int tm = t >> 3, lg = t & 7;
    const int m = m0 + tm;
    if (m >= MMAX) return;
    const int lw = l0 + lg * 8;
    if (lw >= LMAX) return;          // 360 is granule-aligned (45*8)

    short8 re, im;
    #pragma unroll
    for (int e = 0; e < 8; ++e) {
        float2 v = tile[lg * 8 + e][tm];
        re[e] = f2bf(v.x);
        im[e] = f2bf(v.y);
    }
    size_t mb = (size_t)m * (128 * LMAX);
    *(short8*)((short*)xT + mb + (size_t)((f * 2 + 0) * 32 + bc) * LMAX + lw) = re;
    *(short8*)((short*)xT + mb + (size_t)((f * 2 + 1) * 32 + bc) * LMAX + lw) = im;
}

// ---------------------------------------------------------------------------
// gemm1 v9: R13 core + B-staged-once-per-l-chunk (p-halves inner).
//   D[k][c] = sum_l A_p0[k][l]*sgn0*B[src0(c)][l] + A_p1[k][l]*sgn1*B[src1(c)][l]
// Grid (4, 361): K0 = bx*96, m = by. 6 l-chunks of 64; per chunk:
//   {WRITE B(lc)+A(p0,lc); compute p0; WRITE A(p1,lc) [B kept]; compute p1}
// B is sign-free source-indexed (row = src*32+bc, staged straight from xT,
// read once per chunk instead of twice) — xT HBM traffic halved vs R13.
// srcT row-select + sgnT XOR at B-fragment read (correctness proven in R12).
// A prefetch: two hardcoded register sets a0_/a1_ (p0/p1 of next chunk) —
// same register budget as no-spill R13. Stores: R8's proven scalar path.
// ---------------------------------------------------------------------------
__global__ __launch_bounds__(256, 3) void sht_gemm1(
    const float* __restrict__ dpct, const __hip_bfloat16* __restrict__ xT,
    __hip_bfloat16* __restrict__ interQ)
{
    const int m  = blockIdx.y;
    const int K0 = blockIdx.x * 96;

    __shared__ __align__(16) char AlsB[96 * 128];    // [k][64l bf16], 128B rows
    __shared__ __align__(16) char BlsB[128 * 128];   // [src*32+bc][64l bf16]

    const int t    = threadIdx.x;
    const int lane = t & 63;
    const int wave = t >> 6;
    const int wm = (wave >> 1) * 48;   // 3 M-frags
    const int wn = (wave & 1) * 64;    // 4 N-frags
    const int fr = lane & 15;
    const int lq = lane >> 4;

    // A staging: 768 tasks (kd, lo), 3 per thread
    int kdv[3], lov[3], kcl[3];
    #pragma unroll
    for (int it = 0; it < 3; ++it) {
        int task = it * 256 + t;
        kdv[it] = task % 96;
        lov[it] = task / 96;
        kcl[it] = min(K0 + kdv[it], 360);   // clamped k (garbage rows dropped)
    }
    // B staging: row cB = src*32+bc directly (source-indexed, sign-free)
    const int cB  = t >> 1;
    const int g0B = (t & 1) * 4;

    const int            srcT[8] = {0, 1, 2, 3, 3, 2, 1, 0};
    const unsigned short sgnT[8] = {0, 0, 0x8000, 0x8000, 0x8000, 0, 0x8000, 0};

    f32x4 acc[3][4];
    const f32x4 zero = {0.f, 0.f, 0.f, 0.f};
    #pragma unroll
    for (int i = 0; i < 3; ++i)
        #pragma unroll
        for (int j = 0; j < 4; ++j) acc[i][j] = zero;

    // A prefetch: TWO hardcoded register sets (p0 / p1 of one l-chunk)
    float a0_[3][8], a1_[3][8];
    bool  v0_[3],    v1_[3];
    // B prefetch: single set (one per l-chunk)
    short8 bpf[4];
    bool   bvB[4];

#define LOAD_A(AP, LV, pp, lc) {                                               \
    const int l0_ = (lc) * 64;                                                 \
    const size_t rowb_ = ((size_t)(pp) * MMAX + m) * LMAX;                     \
    _Pragma("unroll")                                                          \
    for (int it = 0; it < 3; ++it) {                                           \
        int lb_ = l0_ + lov[it] * 8;                                           \
        LV[it] = (lb_ < LMAX);                                                 \
        int lcl_ = LV[it] ? lb_ : 0;                                           \
        const float* sp_ = dpct + (rowb_ + lcl_) * (size_t)NLAT + kcl[it];     \
        _Pragma("unroll")                                                      \
        for (int e = 0; e < 8; ++e)                                            \
            AP[it][e] = sp_[(size_t)e * NLAT];                                 \
    } }

#define LOAD_B(lc) {                                                           \
    const int l0_ = (lc) * 64;                                                 \
    const short* bb_ = (const short*)xT + (size_t)m * (128 * LMAX) +           \
                       (size_t)cB * LMAX;                                      \
    _Pragma("unroll")                                                          \
    for (int i = 0; i < 4; ++i) {                                              \
        int lg2_ = l0_ + (g0B + i) * 8;                                        \
        bvB[i] = (lg2_ < LMAX);                                                \
        int lcl_ = bvB[i] ? lg2_ : 0;                                          \
        bpf[i] = *(const short8*)(bb_ + lcl_);                                 \
    } }

#define WRITE_A(AP, LV) {                                                      \
    _Pragma("unroll")                                                          \
    for (int it = 0; it < 3; ++it) {                                           \
        short8 w_;                                                             \
        _Pragma("unroll")                                                      \
        for (int e = 0; e < 8; ++e)                                            \
            w_[e] = LV[it] ? f2bf(AP[it][e]) : (short)0;                       \
        int kd_ = kdv[it], lo_ = lov[it];                                      \
        *(short8*)(AlsB + kd_ * 128 + ((lo_ ^ (kd_ & 7)) << 4)) = w_;          \
    } }

#define WRITE_B() {                                                            \
    _Pragma("unroll")                                                          \
    for (int i = 0; i < 4; ++i) {                                              \
        short8 v_ = bpf[i];                                                    \
        _Pragma("unroll")                                                      \
        for (int e = 0; e < 8; ++e) v_[e] = bvB[i] ? v_[e] : (short)0;         \
        int g_ = g0B + i;                                                      \
        *(short8*)(BlsB + cB * 128 + ((g_ ^ (cB & 7)) << 4)) = v_;             \
    } }

    // compute for half pp: B-fragment row/sign selected per (pp, plane)
#define COMPUTE(AF_SRC, pp) {                                                  \
    _Pragma("unroll")                                                          \
    for (int kk = 0; kk < 2; ++kk) {                                           \
        const int g = kk * 4 + lq;                                             \
        short8 af[3];                                                          \
        _Pragma("unroll")                                                      \
        for (int mi = 0; mi < 3; ++mi) {                                       \
            int k = wm + mi * 16 + fr;                                         \
            af[mi] = *(const short8*)(AlsB + k * 128 + ((g ^ (k & 7)) << 4));  \
        }                                                                      \
        _Pragma("unroll")                                                      \
        for (int ni = 0; ni < 4; ++ni) {                                       \
            int pl_ = 2 * (wave & 1) + (ni >> 1);                              \
            int rB_ = srcT[(pp) * 4 + pl_] * 32 + (ni & 1) * 16 + fr;          \
            short8 bg = *(const short8*)(                                      \
                BlsB + rB_ * 128 + ((g ^ (rB_ & 7)) << 4));                    \
            short sg_ = (short)sgnT[(pp) * 4 + pl_];                           \
            _Pragma("unroll")                                                  \
            for (int e = 0; e < 8; ++e) bg[e] ^= sg_;                          \
            _Pragma("unroll")                                                  \
            for (int mi = 0; mi < 3; ++mi)                                     \
                acc[mi][ni] = __builtin_amdgcn_mfma_f32_16x16x32_bf16(         \
                    af[mi], bg, acc[mi][ni], 0, 0, 0);                         \
        }                                                                      \
    } }

    // prologue: chunk 0 loads
    LOAD_B(0);
    LOAD_A(a0_, v0_, 0, 0);
    LOAD_A(a1_, v1_, 1, 0);

    #pragma unroll 1
    for (int lc = 0; lc < 6; ++lc) {
        // ---- stage B(lc) + A(p0, lc) ----
        __syncthreads();                      // prior chunk's LDS reads done
        WRITE_B();
        WRITE_A(a0_, v0_);
        __syncthreads();
        if (lc < 5) {
            LOAD_B(lc + 1);                   // refill B for next chunk
            LOAD_A(a0_, v0_, 0, lc + 1);      // refill A-p0 for next chunk
        }
        COMPUTE(a0_, 0);                      // p = 0 against B(lc)

        // ---- stage A(p1, lc), B untouched ----
        __syncthreads();                      // p0 reads done before A rewrite
        WRITE_A(a1_, v1_);
        __syncthreads();
        if (lc < 5) LOAD_A(a1_, v1_, 1, lc + 1);
        COMPUTE(a1_, 1);                      // p = 1 against same B(lc)
    }

#undef LOAD_A
#undef LOAD_B
#undef WRITE_A
#undef WRITE_B
#undef COMPUTE

    // store (R8 proven scalar path): k = K0 + wm + mi*16 + lq*4 + r
    #pragma unroll
    for (int mi = 0; mi < 3; ++mi) {
        int kr = K0 + wm + mi * 16 + lq * 4;
        #pragma unroll
        for (int ni = 0; ni < 4; ++ni) {
            int c = wn + ni * 16 + fr;
            int pl = c >> 5, bc = c & 31;
            int ri = pl & 1, tt = pl >> 1;
            size_t qb = (size_t)(2 * m + ri) * MT + (size_t)(bc * 2 + tt) * NLAT;
            #pragma unroll
            for (int r = 0; r < 4; ++r) {
                int k = kr + r;
                if (k < NLAT)
                    interQ[qb + k] = __float2bfloat16(acc[mi][ni][r]);
            }
        }
    }
}

// ---------------------------------------------------------------------------
// Transpose interQ [722][23104] -> interT [23104][736] (zero K-pad)  [R8]
// ---------------------------------------------------------------------------
__global__ __launch_bounds__(256) void sht_transpose(
    const __hip_bfloat16* __restrict__ inQ, __hip_bfloat16* __restrict__ outT)
{
    __shared__ __hip_bfloat16 tile[64][65];
    const int R0 = blockIdx.x * 64;
    const int q0 = blockIdx.y * 64;
    const int tx = threadIdx.x & 63;
    const int ty = threadIdx.x >> 6;
    const __hip_bfloat16 zv = __float2bfloat16(0.f);

    for (int qq = ty; qq < 64; qq += 4) {
        int q = q0 + qq;
        tile[qq][tx] = (q < QT) ? inQ[(size_t)q * MT + R0 + tx] : zv;
    }
    __syncthreads();
    if (q0 + tx < KP) {
        for (int rr = ty; rr < 64; rr += 4) {
            outT[(size_t)(R0 + rr) * KP + q0 + tx] = tile[tx][rr];
        }
    }
}

// ---------------------------------------------------------------------------
// W table [NP=768][KP=736] bf16
// ---------------------------------------------------------------------------
__global__ __launch_bounds__(256) void sht_make_w(__hip_bfloat16* __restrict__ W)
{
    const int idx = blockIdx.x * 256 + threadIdx.x;
    const int j = idx / KP;
    const int q = idx % KP;
    float v = 0.f;
    if (j < NLON && q < QT) {
        int m = q >> 1;
        float coef = (m == 0 || m == 360) ? 1.f : 2.f;
        int ph = (m * j) % 720;
        float ang = (float)ph * (float)(2.0 * M_PI / 720.0);
        float s, c;
        __sincosf(ang, &s, &c);
        v = (q & 1) ? (-coef * s) : (coef * c);
    }
    W[idx] = __float2bfloat16(v);
}

// ---------------------------------------------------------------------------
// Stage 2 GEMM (unchanged, proven): out[R][j] = sum_q interT[R][q] * W[j][q]
// ---------------------------------------------------------------------------
__global__ __launch_bounds__(256) void sht_gemm(
    const __hip_bfloat16* __restrict__ A,   // [MT][KP]
    const __hip_bfloat16* __restrict__ W,   // [NP][KP]
    float* __restrict__ out)                // [MT][NLON]
{
    __shared__ __align__(16) __hip_bfloat16 As[BM * BK];
    __shared__ __align__(16) __hip_bfloat16 Bs[BN * BK];
    const int t  = threadIdx.x;
    const int R0 = blockIdx.x * BM;
    const int J0 = blockIdx.y * BN;

    const int rowA = t >> 2;
    const int kc   = (t & 3) * 8;
    const int gr0  = min(R0 + rowA,      MT - 1);
    const int gr1  = min(R0 + rowA + 64, MT - 1);
    const __hip_bfloat16* pa0 = A + (size_t)gr0 * KP + kc;
    const __hip_bfloat16* pa1 = A + (size_t)gr1 * KP + kc;
    const __hip_bfloat16* pb0 = W + (size_t)(J0 + rowA) * KP + kc;
    const __hip_bfloat16* pb1 = W + (size_t)(J0 + rowA + 64) * KP + kc;

    const int lane = t & 63;
    const int wave = t >> 6;
    const int wm = (wave >> 1) * 64;
    const int wn = (wave & 1) * 64;
    const int fr = lane & 15;
    const int kg = (lane >> 4) * 8;

    f32x4 acc[4][4];
    const f32x4 zero = {0.f, 0.f, 0.f, 0.f};
    #pragma unroll
    for (int i = 0; i < 4; ++i)
        #pragma unroll
        for (int j = 0; j < 4; ++j) acc[i][j] = zero;

    short8 va0 = *(const short8*)pa0;
    short8 va1 = *(const short8*)pa1;
    short8 vb0 = *(const short8*)pb0;
    short8 vb1 = *(const short8*)pb1;

    for (int kt = 0; kt < KP / BK; ++kt) {
        __syncthreads();
        *(short8*)&As[t * 8]        = va0;
        *(short8*)&As[t * 8 + 2048] = va1;
        *(short8*)&Bs[t * 8]        = vb0;
        *(short8*)&Bs[t * 8 + 2048] = vb1;
        __syncthreads();

        if (kt + 1 < KP / BK) {
            const int ko = (kt + 1) * BK;
            va0 = *(const short8*)(pa0 + ko);
            va1 = *(const short8*)(pa1 + ko);
            vb0 = *(const short8*)(pb0 + ko);
            vb1 = *(const short8*)(pb1 + ko);
        }

        short8 af[4], bg[4];
        #pragma unroll
        for (int i = 0; i < 4; ++i)
            af[i] = *(const short8*)&As[(wm + i * 16 + fr) * BK + kg];
        #pragma unroll
        for (int i = 0; i < 4; ++i)
            bg[i] = *(const short8*)&Bs[(wn + i * 16 + fr) * BK + kg];

        #pragma unroll
        for (int mi = 0; mi < 4; ++mi)
            #pragma unroll
            for (int ni = 0; ni < 4; ++ni)
                acc[mi][ni] = __builtin_amdgcn_mfma_f32_16x16x32_bf16(
                    af[mi], bg[ni], acc[mi][ni], 0, 0, 0);
    }

    const int orow = (lane >> 4) * 4;
    #pragma unroll
    for (int mi = 0; mi < 4; ++mi) {
        #pragma unroll
        for (int ni = 0; ni < 4; ++ni) {
            #pragma unroll
            for (int r = 0; r < 4; ++r) {
                int row = R0 + wm + mi * 16 + orow + r;
                int col = J0 + wn + ni * 16 + fr;
                if (row < MT && col < NLON)
                    out[(size_t)row * NLON + col] = acc[mi][ni][r];
            }
        }
    }
}

// ---------------------------------------------------------------------------
// Workspace layout (R8 proven):
//   region A [0, 34,009,088):  xT (33,269,760 B)  then interT (34,009,088 B)
//   region B [34,009,088, 67,371,264):  interQ (33,362,176 B) then W
// Liveness: xT:[prep->gemm1]  interQ:[gemm1->transpose]
//           interT:[transpose->gemm2]  W:[make_w->gemm2] (interQ dead by then)
// ---------------------------------------------------------------------------
extern "C" void kernel_launch(void* const* d_in, const int* in_sizes, int n_in,
                              void* d_out, int out_size, void* d_ws, size_t ws_size,
                              hipStream_t stream)
{
    const float* x    = (const float*)d_in[0];
    const float* dpct = (const float*)d_in[1];
    float* out        = (float*)d_out;

    char* ws = (char*)d_ws;
    __hip_bfloat16* xT     = (__hip_bfloat16*)ws;
    __hip_bfloat16* interT = (__hip_bfloat16*)ws;
    __hip_bfloat16* interQ = (__hip_bfloat16*)(ws + 34009088);
    __hip_bfloat16* Wt     = (__hip_bfloat16*)(ws + 34009088);

    dim3 gp(12, 6, 64);
    sht_prep_x<<<gp, 256, 0, stream>>>(x, xT);

    dim3 g1(4, MMAX);
    sht_gemm1<<<g1, 256, 0, stream>>>(dpct, xT, interQ);

    dim3 gt(MT / 64, 12);
    sht_transpose<<<gt, 256, 0, stream>>>(interQ, interT);

    sht_make_w<<<(NP * KP) / 256, 256, 0, stream>>>(Wt);

    dim3 gg((MT + BM - 1) / BM, NP / BN);
    sht_gemm<<<gg, 256, 0, stream>>>(interT, Wt, out);
}

// Round 15
// 311.437 us; speedup vs baseline: 1.1020x; 1.1020x over previous
//
#include <hip/hip_runtime.h>
#include <hip/hip_bf16.h>
#include <math.h>

#define LMAX 360
#define MMAX 361
#define NLAT 361
#define NLON 720
#define BC   32
#define MT   (BC*2*NLAT)    // 23104 real rows
#define NLATP 384           // padded k-stride: 768 B = 12 full 64-B lines
#define MTP  (BC*2*NLATP)   // 24576 padded row-elems per q-plane
#define QT   722            // valid K (2*MMAX) for stage-2 GEMM
#define KP   736            // stage-2 padded K = 23*32
#define NP   768            // stage-2 padded N
#define BM   128
#define BN   128
#define BK   32

typedef __attribute__((ext_vector_type(8))) short short8;
typedef __attribute__((ext_vector_type(4))) short short4v;
typedef __attribute__((ext_vector_type(4))) float f32x4;

static __device__ __forceinline__ short f2bf(float v) {
    __hip_bfloat16 h = __float2bfloat16(v);
    return *reinterpret_cast<short*>(&h);
}

// ---------------------------------------------------------------------------
// prep_x (unchanged, proven): x fp32 [bc][f][l][m][ri] -> xT bf16
// [m][src*32+bc][l], src = f*2 + ri, rows 360 bf16 = 720 B.
// ---------------------------------------------------------------------------
__global__ __launch_bounds__(256) void sht_prep_x(
    const float* __restrict__ x, __hip_bfloat16* __restrict__ xT)
{
    const int m0 = blockIdx.x * 32;
    const int l0 = blockIdx.y * 64;
    const int bc = blockIdx.z >> 1, f = blockIdx.z & 1;
    __shared__ float2 tile[64][33];
    const float2* __restrict__ x2 = (const float2*)x;
    const int t = threadIdx.x;
    const int rm = t & 31, rl = t >> 5;

    const int mm = min(m0 + rm, MMAX - 1);
    #pragma unroll
    for (int r = 0; r < 8; ++r) {
        int l = min(l0 + rl + r * 8, LMAX - 1);
        tile[rl + r * 8][rm] = x2[((size_t)(bc * 2 + f) * LMAX + l) * MMAX + mm];
    }
    __syncthreads();

    const int tm = t >> 3, lg = t & 7;
    const int m = m0 + tm;
    if (m >= MMAX) return;
    const int lw = l0 + lg * 8;
    if (lw >= LMAX) return;          // 360 is granule-aligned (45*8)

    short8 re, im;
    #pragma unroll
    for (int e = 0; e < 8; ++e) {
        float2 v = tile[lg * 8 + e][tm];
        re[e] = f2bf(v.x);
        im[e] = f2bf(v.y);
    }
    size_t mb = (size_t)m * (128 * LMAX);
    *(short8*)((short*)xT + mb + (size_t)((f * 2 + 0) * 32 + bc) * LMAX + lw) = re;
    *(short8*)((short*)xT + mb + (size_t)((f * 2 + 1) * 32 + bc) * LMAX + lw) = im;
}

// ---------------------------------------------------------------------------
// gemm1 (R13 core byte-identical: depth-2 A prefetch, grid (4,361), no spill;
// ONLY the store geometry changed): per-m MFMA GEMM.
//   D[k][combo] = sum_{l'} A[k][l'] * B[combo][l'], K = 768 (two 384 halves)
// interQ rows padded to NLATP=384 (768 B, line-aligned): each K-block's
// 96-elem chunk = bytes [K0*192, K0*192+192) = exactly 3 whole 64-B lines.
// ZERO line sharing between blocks -> no RMW, no write amplification.
// ---------------------------------------------------------------------------
__global__ __launch_bounds__(256, 3) void sht_gemm1(
    const float* __restrict__ dpct, const __hip_bfloat16* __restrict__ xT,
    __hip_bfloat16* __restrict__ interQ)
{
    const int m  = blockIdx.y;
    const int K0 = blockIdx.x * 96;

    __shared__ __align__(16) char AlsB[96 * 128];    // [k][64l bf16], 128B rows
    __shared__ __align__(16) char BlsB[128 * 128];   // [c][64l bf16]

    const int t    = threadIdx.x;
    const int lane = t & 63;
    const int wave = t >> 6;
    const int wm = (wave >> 1) * 48;   // 3 M-frags
    const int wn = (wave & 1) * 64;    // 4 N-frags
    const int fr = lane & 15;
    const int lq = lane >> 4;

    // A staging: 768 tasks (kd, lo), 3 per thread
    int kdv[3], lov[3], kcl[3];
    #pragma unroll
    for (int it = 0; it < 3; ++it) {
        int task = it * 256 + t;
        kdv[it] = task % 96;
        lov[it] = task / 96;
        kcl[it] = min(K0 + kdv[it], 360);   // clamped k (garbage rows dropped)
    }
    // B staging: c = t>>1, granules g0B..g0B+3
    const int cB    = t >> 1;
    const int plane = cB >> 5, bcq = cB & 31;
    const int g0B   = (t & 1) * 4;

    const int            srcT[8] = {0, 1, 2, 3, 3, 2, 1, 0};
    const unsigned short sgnT[8] = {0, 0, 0x8000, 0x8000, 0x8000, 0, 0x8000, 0};

    f32x4 acc[3][4];
    const f32x4 zero = {0.f, 0.f, 0.f, 0.f};
    #pragma unroll
    for (int i = 0; i < 3; ++i)
        #pragma unroll
        for (int j = 0; j < 4; ++j) acc[i][j] = zero;

    // A prefetch: TWO hardcoded register sets (no pointer indirection!)
    float a0_[3][8], a1_[3][8];
    bool  v0_[3],    v1_[3];
    // B prefetch: single set
    short8 bpf[4];
    bool   bvB[4];
    short  bsgn = 0;

#define STEP_P(s)  ((s) >= 6 ? 1 : 0)
#define STEP_L(s)  (((s) % 6) * 64)

#define LOAD_A(AP, LV, ss) {                                                   \
    const int p_ = STEP_P(ss); const int l0_ = STEP_L(ss);                     \
    const size_t rowb_ = ((size_t)p_ * MMAX + m) * LMAX;                       \
    _Pragma("unroll")                                                          \
    for (int it = 0; it < 3; ++it) {                                           \
        int lb_ = l0_ + lov[it] * 8;                                           \
        LV[it] = (lb_ < LMAX);                                                 \
        int lcl_ = LV[it] ? lb_ : 0;                                           \
        const float* sp_ = dpct + (rowb_ + lcl_) * (size_t)NLAT + kcl[it];     \
        _Pragma("unroll")                                                      \
        for (int e = 0; e < 8; ++e)                                            \
            AP[it][e] = sp_[(size_t)e * NLAT];                                 \
    } }

#define LOAD_B(ss) {                                                           \
    const int p_ = STEP_P(ss); const int l0_ = STEP_L(ss);                     \
    int src_ = srcT[p_ * 4 + plane];                                           \
    bsgn = (short)sgnT[p_ * 4 + plane];                                        \
    const short* bb_ = (const short*)xT + (size_t)m * (128 * LMAX) +           \
                       (size_t)(src_ * 32 + bcq) * LMAX;                       \
    _Pragma("unroll")                                                          \
    for (int i = 0; i < 4; ++i) {                                              \
        int lg2_ = l0_ + (g0B + i) * 8;                                        \
        bvB[i] = (lg2_ < LMAX);                                                \
        int lcl_ = bvB[i] ? lg2_ : 0;                                          \
        bpf[i] = *(const short8*)(bb_ + lcl_);                                 \
    } }

#define WRITE_A(AP, LV) {                                                      \
    _Pragma("unroll")                                                          \
    for (int it = 0; it < 3; ++it) {                                           \
        short8 w_;                                                             \
        _Pragma("unroll")                                                      \
        for (int e = 0; e < 8; ++e)                                            \
            w_[e] = LV[it] ? f2bf(AP[it][e]) : (short)0;                       \
        int kd_ = kdv[it], lo_ = lov[it];                                      \
        *(short8*)(AlsB + kd_ * 128 + ((lo_ ^ (kd_ & 7)) << 4)) = w_;          \
    } }

#define WRITE_B() {                                                            \
    _Pragma("unroll")                                                          \
    for (int i = 0; i < 4; ++i) {                                              \
        short8 v_ = bpf[i];                                                    \
        _Pragma("unroll")                                                      \
        for (int e = 0; e < 8; ++e) {                                          \
            short xe_ = (short)(v_[e] ^ bsgn);                                 \
            v_[e] = bvB[i] ? xe_ : (short)0;                                   \
        }                                                                      \
        int g_ = g0B + i;                                                      \
        *(short8*)(BlsB + cB * 128 + ((g_ ^ (cB & 7)) << 4)) = v_;             \
    } }

    auto compute = [&]() {
        #pragma unroll
        for (int kk = 0; kk < 2; ++kk) {
            short8 af[3], bg[4];
            const int g = kk * 4 + lq;
            #pragma unroll
            for (int mi = 0; mi < 3; ++mi) {
                int k = wm + mi * 16 + fr;
                af[mi] = *(const short8*)(AlsB + k * 128 + ((g ^ (k & 7)) << 4));
            }
            #pragma unroll
            for (int ni = 0; ni < 4; ++ni) {
                int c = wn + ni * 16 + fr;
                bg[ni] = *(const short8*)(BlsB + c * 128 + ((g ^ (c & 7)) << 4));
            }
            #pragma unroll
            for (int mi = 0; mi < 3; ++mi)
                #pragma unroll
                for (int ni = 0; ni < 4; ++ni)
                    acc[mi][ni] = __builtin_amdgcn_mfma_f32_16x16x32_bf16(
                        af[mi], bg[ni], acc[mi][ni], 0, 0, 0);
        }
    };

    // prologue: B(0), A-set0(0), A-set1(1)
    LOAD_B(0);
    LOAD_A(a0_, v0_, 0);
    LOAD_A(a1_, v1_, 1);

    #pragma unroll 1
    for (int s = 0; s < 12; s += 2) {
        // ---- even step s: A-set0, B holds step s ----
        __syncthreads();
        WRITE_A(a0_, v0_);
        WRITE_B();
        __syncthreads();
        if (s + 1 < 12) LOAD_B(s + 1);          // B first (shallow)
        if (s + 2 < 12) LOAD_A(a0_, v0_, s + 2); // deep A prefetch
        compute();

        // ---- odd step s+1: A-set1, B holds step s+1 ----
        __syncthreads();
        WRITE_A(a1_, v1_);
        WRITE_B();
        __syncthreads();
        if (s + 2 < 12) LOAD_B(s + 2);
        if (s + 3 < 12) LOAD_A(a1_, v1_, s + 3);
        compute();
    }

#undef LOAD_A
#undef LOAD_B
#undef WRITE_A
#undef WRITE_B
#undef STEP_P
#undef STEP_L

    // store (packed 8-B, line-aligned rows): k = K0 + wm + mi*16 + lq*4 + r
    // row byte-stride 768 (12 lines); this block touches only its own 3 lines
    // per row -> no inter-block line sharing, no RMW.
    #pragma unroll
    for (int mi = 0; mi < 3; ++mi) {
        int kr = K0 + wm + mi * 16 + lq * 4;
        #pragma unroll
        for (int ni = 0; ni < 4; ++ni) {
            int c = wn + ni * 16 + fr;
            int pl = c >> 5, bc = c & 31;
            int ri = pl & 1, tt = pl >> 1;
            size_t qb = (size_t)(2 * m + ri) * MTP + (size_t)(bc * 2 + tt) * NLATP;
            if (kr + 3 <= 360) {
                short4v w;
                #pragma unroll
                for (int r = 0; r < 4; ++r) w[r] = f2bf(acc[mi][ni][r]);
                *(short4v*)((short*)interQ + qb + kr) = w;
            } else if (kr <= 360) {   // kr == 360 (4-aligned): single element
                ((short*)interQ)[qb + kr] = f2bf(acc[mi][ni][0]);
            }
        }
    }
}

// ---------------------------------------------------------------------------
// Transpose interQ [722][MTP padded-384] -> interT [23104 compact][736]
// Rm maps compact row R to padded row: Rm = (R/361)*384 + R%361.
// ---------------------------------------------------------------------------
__global__ __launch_bounds__(256) void sht_transpose(
    const __hip_bfloat16* __restrict__ inQ, __hip_bfloat16* __restrict__ outT)
{
    __shared__ __hip_bfloat16 tile[64][65];
    const int R0 = blockIdx.x * 64;
    const int q0 = blockIdx.y * 64;
    const int tx = threadIdx.x & 63;
    const int ty = threadIdx.x >> 6;
    const __hip_bfloat16 zv = __float2bfloat16(0.f);

    const int R  = R0 + tx;
    const int Rm = (R / NLAT) * NLATP + (R % NLAT);

    for (int qq = ty; qq < 64; qq += 4) {
        int q = q0 + qq;
        tile[qq][tx] = (q < QT) ? inQ[(size_t)q * MTP + Rm] : zv;
    }
    __syncthreads();
    if (q0 + tx < KP) {
        for (int rr = ty; rr < 64; rr += 4) {
            outT[(size_t)(R0 + rr) * KP + q0 + tx] = tile[tx][rr];
        }
    }
}

// ---------------------------------------------------------------------------
// W table [NP=768][KP=736] bf16
// ---------------------------------------------------------------------------
__global__ __launch_bounds__(256) void sht_make_w(__hip_bfloat16* __restrict__ W)
{
    const int idx = blockIdx.x * 256 + threadIdx.x;
    const int j = idx / KP;
    const int q = idx % KP;
    float v = 0.f;
    if (j < NLON && q < QT) {
        int m = q >> 1;
        float coef = (m == 0 || m == 360) ? 1.f : 2.f;
        int ph = (m * j) % 720;
        float ang = (float)ph * (float)(2.0 * M_PI / 720.0);
        float s, c;
        __sincosf(ang, &s, &c);
        v = (q & 1) ? (-coef * s) : (coef * c);
    }
    W[idx] = __float2bfloat16(v);
}

// ---------------------------------------------------------------------------
// Stage 2 GEMM (unchanged, proven): out[R][j] = sum_q interT[R][q] * W[j][q]
// ---------------------------------------------------------------------------
__global__ __launch_bounds__(256) void sht_gemm(
    const __hip_bfloat16* __restrict__ A,   // [MT][KP]
    const __hip_bfloat16* __restrict__ W,   // [NP][KP]
    float* __restrict__ out)                // [MT][NLON]
{
    __shared__ __align__(16) __hip_bfloat16 As[BM * BK];
    __shared__ __align__(16) __hip_bfloat16 Bs[BN * BK];
    const int t  = threadIdx.x;
    const int R0 = blockIdx.x * BM;
    const int J0 = blockIdx.y * BN;

    const int rowA = t >> 2;
    const int kc   = (t & 3) * 8;
    const int gr0  = min(R0 + rowA,      MT - 1);
    const int gr1  = min(R0 + rowA + 64, MT - 1);
    const __hip_bfloat16* pa0 = A + (size_t)gr0 * KP + kc;
    const __hip_bfloat16* pa1 = A + (size_t)gr1 * KP + kc;
    const __hip_bfloat16* pb0 = W + (size_t)(J0 + rowA) * KP + kc;
    const __hip_bfloat16* pb1 = W + (size_t)(J0 + rowA + 64) * KP + kc;

    const int lane = t & 63;
    const int wave = t >> 6;
    const int wm = (wave >> 1) * 64;
    const int wn = (wave & 1) * 64;
    const int fr = lane & 15;
    const int kg = (lane >> 4) * 8;

    f32x4 acc[4][4];
    const f32x4 zero = {0.f, 0.f, 0.f, 0.f};
    #pragma unroll
    for (int i = 0; i < 4; ++i)
        #pragma unroll
        for (int j = 0; j < 4; ++j) acc[i][j] = zero;

    short8 va0 = *(const short8*)pa0;
    short8 va1 = *(const short8*)pa1;
    short8 vb0 = *(const short8*)pb0;
    short8 vb1 = *(const short8*)pb1;

    for (int kt = 0; kt < KP / BK; ++kt) {
        __syncthreads();
        *(short8*)&As[t * 8]        = va0;
        *(short8*)&As[t * 8 + 2048] = va1;
        *(short8*)&Bs[t * 8]        = vb0;
        *(short8*)&Bs[t * 8 + 2048] = vb1;
        __syncthreads();

        if (kt + 1 < KP / BK) {
            const int ko = (kt + 1) * BK;
            va0 = *(const short8*)(pa0 + ko);
            va1 = *(const short8*)(pa1 + ko);
            vb0 = *(const short8*)(pb0 + ko);
            vb1 = *(const short8*)(pb1 + ko);
        }

        short8 af[4], bg[4];
        #pragma unroll
        for (int i = 0; i < 4; ++i)
            af[i] = *(const short8*)&As[(wm + i * 16 + fr) * BK + kg];
        #pragma unroll
        for (int i = 0; i < 4; ++i)
            bg[i] = *(const short8*)&Bs[(wn + i * 16 + fr) * BK + kg];

        #pragma unroll
        for (int mi = 0; mi < 4; ++mi)
            #pragma unroll
            for (int ni = 0; ni < 4; ++ni)
                acc[mi][ni] = __builtin_amdgcn_mfma_f32_16x16x32_bf16(
                    af[mi], bg[ni], acc[mi][ni], 0, 0, 0);
    }

    const int orow = (lane >> 4) * 4;
    #pragma unroll
    for (int mi = 0; mi < 4; ++mi) {
        #pragma unroll
        for (int ni = 0; ni < 4; ++ni) {
            #pragma unroll
            for (int r = 0; r < 4; ++r) {
                int row = R0 + wm + mi * 16 + orow + r;
                int col = J0 + wn + ni * 16 + fr;
                if (row < MT && col < NLON)
                    out[(size_t)row * NLON + col] = acc[mi][ni][r];
            }
        }
    }
}

// ---------------------------------------------------------------------------
// Workspace layout (R9 proved ws >= 280,297,728 B usable):
//   xT     [0,           33,269,760)
//   interT [34,009,088,  68,018,176)
//   interQ [70,254,592, 105,742,336)   padded [722][MTP=24576] bf16
//   W      [105,906,176, 107,036,672)
// Liveness: xT:[prep->gemm1]  interQ:[gemm1->transpose]
//           interT:[transpose->gemm2]  W:[make_w->gemm2]
// ---------------------------------------------------------------------------
extern "C" void kernel_launch(void* const* d_in, const int* in_sizes, int n_in,
                              void* d_out, int out_size, void* d_ws, size_t ws_size,
                              hipStream_t stream)
{
    const float* x    = (const float*)d_in[0];
    const float* dpct = (const float*)d_in[1];
    float* out        = (float*)d_out;

    char* ws = (char*)d_ws;
    __hip_bfloat16* xT     = (__hip_bfloat16*)ws;
    __hip_bfloat16* interT = (__hip_bfloat16*)(ws + 34009088);
    __hip_bfloat16* interQ = (__hip_bfloat16*)(ws + 70254592);
    __hip_bfloat16* Wt     = (__hip_bfloat16*)(ws + 105906176);

    dim3 gp(12, 6, 64);
    sht_prep_x<<<gp, 256, 0, stream>>>(x, xT);

    dim3 g1(4, MMAX);   // K0 fast: same-m blocks adjacent (read-side L3 reuse)
    sht_gemm1<<<g1, 256, 0, stream>>>(dpct, xT, interQ);

    dim3 gt(MT / 64, 12);
    sht_transpose<<<gt, 256, 0, stream>>>(interQ, interT);

    sht_make_w<<<(NP * KP) / 256, 256, 0, stream>>>(Wt);

    dim3 gg((MT + BM - 1) / BM, NP / BN);
    sht_gemm<<<gg, 256, 0, stream>>>(interT, Wt, out);
}

// Round 16
// 282.023 us; speedup vs baseline: 1.2169x; 1.1043x over previous
//
#include <hip/hip_runtime.h>
#include <hip/hip_bf16.h>
#include <math.h>

#define LMAX 360
#define MMAX 361
#define NLAT 361
#define NLON 720
#define BC   32
#define MT   (BC*2*NLAT)   // 23104 rows
#define QT   722           // valid K (2*MMAX) for stage-2 GEMM
#define KP   736           // stage-2 padded K = 23*32
#define NP   768           // stage-2 padded N
#define BM   128
#define BN   128
#define BK   32
#define AS   80            // gemm1 A-LDS row stride (64B data + 16B pad)

typedef __attribute__((ext_vector_type(8))) short short8;
typedef __attribute__((ext_vector_type(4))) float f32x4;

static __device__ __forceinline__ short f2bf(float v) {
    __hip_bfloat16 h = __float2bfloat16(v);
    return *reinterpret_cast<short*>(&h);
}

// ---------------------------------------------------------------------------
// prep_x (unchanged, proven): x fp32 [bc][f][l][m][ri] -> xT bf16
// [m][src*32+bc][l], src = f*2 + ri, rows 360 bf16 = 720 B.
// ---------------------------------------------------------------------------
__global__ __launch_bounds__(256) void sht_prep_x(
    const float* __restrict__ x, __hip_bfloat16* __restrict__ xT)
{
    const int m0 = blockIdx.x * 32;
    const int l0 = blockIdx.y * 64;
    const int bc = blockIdx.z >> 1, f = blockIdx.z & 1;
    __shared__ float2 tile[64][33];
    const float2* __restrict__ x2 = (const float2*)x;
    const int t = threadIdx.x;
    const int rm = t & 31, rl = t >> 5;

    const int mm = min(m0 + rm, MMAX - 1);
    #pragma unroll
    for (int r = 0; r < 8; ++r) {
        int l = min(l0 + rl + r * 8, LMAX - 1);
        tile[rl + r * 8][rm] = x2[((size_t)(bc * 2 + f) * LMAX + l) * MMAX + mm];
    }
    __syncthreads();

    const int tm = t >> 3, lg = t & 7;
    const int m = m0 + tm;
    if (m >= MMAX) return;
    const int lw = l0 + lg * 8;
    if (lw >= LMAX) return;          // 360 is granule-aligned (45*8)

    short8 re, im;
    #pragma unroll
    for (int e = 0; e < 8; ++e) {
        float2 v = tile[lg * 8 + e][tm];
        re[e] = f2bf(v.x);
        im[e] = f2bf(v.y);
    }
    size_t mb = (size_t)m * (128 * LMAX);
    *(short8*)((short*)xT + mb + (size_t)((f * 2 + 0) * 32 + bc) * LMAX + lw) = re;
    *(short8*)((short*)xT + mb + (size_t)((f * 2 + 1) * 32 + bc) * LMAX + lw) = im;
}

// ---------------------------------------------------------------------------
// gemm1 v10: ONE block per m (grid 361, 512 thr, 8 waves).
//   out[k][c] = sum_{p,l} dpct[p][m][l][k] * sgn(p,pl(c)) * xT[m][src(p,pl)*32+bc][l]
// B (whole 92-KB xT m-panel) copied to LDS ONCE, sign-free; src/sign applied
// at fragment read (R14-proven mapping). A: 24 chunks (2p x 12) of 32 l;
// staging reads WHOLE dpct rows (4-row groups = 361 aligned float4s,
// sequential sweep) and scatter-transposes to LDS [k][l32] (stride 80 B:
// b128 frag reads 2-way-free; b16 writes ~8-way spread).
// Wave tile: 48 k x 128 c (3x8 frags, acc 96 VGPR). 8 waves cover 384 k.
// k rows 361..383 are garbage -> discarded at store (k<361).
// ---------------------------------------------------------------------------
__global__ __launch_bounds__(512, 1) void sht_gemm1(
    const float* __restrict__ dpct, const __hip_bfloat16* __restrict__ xT,
    __hip_bfloat16* __restrict__ interQ)
{
    const int m = blockIdx.x;

    __shared__ __align__(16) char Bls[128 * 720];   // 92160 B, sign-free panel
    __shared__ __align__(16) char Als[384 * AS];    // 30720 B, [k][l32]

    const int t    = threadIdx.x;
    const int lane = t & 63;
    const int wave = t >> 6;
    const int fr = lane & 15;
    const int lq = lane >> 4;

    // A-staging task constants: l-group ag (4 rows), j = float4 index in group
    const int ag = (wave & 1) * 4 + lq;          // 0..7 -> l_rel = 4*ag+loff
    const int jb = fr + (wave >> 1) * 16;        // 0..63
    int  aj[6];
    bool av[6];
    #pragma unroll
    for (int i = 0; i < 6; ++i) { aj[i] = jb + i * 64; av[i] = (aj[i] <= 360); }
    const bool gtail = (ag < 2);                 // tail chunk: only l_rel 0..7

    const int            srcT[8] = {0, 1, 2, 3, 3, 2, 1, 0};
    const unsigned short sgnT[8] = {0, 0, 0x8000, 0x8000, 0x8000, 0, 0x8000, 0};

    // ---- B copy: xT m-panel -> LDS, linear, sign-free ----
    {
        const short8* src8 = (const short8*)((const short*)xT +
                                             (size_t)m * (128 * LMAX));
        #pragma unroll
        for (int i = 0; i < 12; ++i) {
            int idx = t + i * 512;
            if (idx < 5760) *(short8*)(Bls + idx * 16) = src8[idx];
        }
    }

    f32x4 acc[3][8];
    const f32x4 zero = {0.f, 0.f, 0.f, 0.f};
    #pragma unroll
    for (int i = 0; i < 3; ++i)
        #pragma unroll
        for (int j = 0; j < 8; ++j) acc[i][j] = zero;

    float4 apf[6];
    short8 z8_;
    #pragma unroll
    for (int e = 0; e < 8; ++e) z8_[e] = 0;

    // load chunk (pp, ch): 4-row-group ag, float4 j; clamp invalid to offset 0
#define LOAD_A(pp, ch) {                                                       \
    const float* cb_ = dpct + (((size_t)(pp) * MMAX + m) * LMAX + (ch) * 32)   \
                              * (size_t)NLAT;                                  \
    const bool tl_ = ((ch) == 11);                                             \
    _Pragma("unroll")                                                          \
    for (int i = 0; i < 6; ++i) {                                              \
        bool ok_ = av[i] && (!tl_ || gtail);                                   \
        size_t off_ = ok_ ? ((size_t)ag * 1444 + (size_t)aj[i] * 4) : 0;       \
        apf[i] = *(const float4*)(cb_ + off_);                                 \
    } }

#define WR_E(ii, ee, val) {                                                    \
    int d4_ = aj[ii] * 4 + (ee);                                               \
    int lo_ = (d4_ >= 361) + (d4_ >= 722) + (d4_ >= 1083);                     \
    int k_  = d4_ - 361 * lo_;                                                 \
    int lr_ = ag * 4 + lo_;                                                    \
    *(short*)(Als + k_ * AS + lr_ * 2) = f2bf(val); }

#define WRITE_A(ch) {                                                          \
    const bool tl_ = ((ch) == 11);                                             \
    _Pragma("unroll")                                                          \
    for (int i = 0; i < 6; ++i) {                                              \
        if (av[i] && (!tl_ || gtail)) {                                        \
            WR_E(i, 0, apf[i].x) WR_E(i, 1, apf[i].y)                          \
            WR_E(i, 2, apf[i].z) WR_E(i, 3, apf[i].w)                          \
        }                                                                      \
    }                                                                          \
    if (tl_) {                                                                 \
        _Pragma("unroll")                                                      \
        for (int h = 0; h < 3; ++h) {                                          \
            int z_ = t + h * 512;                                              \
            if (z_ < 1152) {                                                   \
                int zr_ = z_, zp_ = 0;                                         \
                if (z_ >= 768)      { zr_ = z_ - 768; zp_ = 2; }               \
                else if (z_ >= 384) { zr_ = z_ - 384; zp_ = 1; }               \
                *(short8*)(Als + zr_ * AS + 16 + zp_ * 16) = z8_;              \
            }                                                                  \
        }                                                                      \
    } }

#define COMPUTE(pp, ch) {                                                      \
    short8 af[3];                                                              \
    _Pragma("unroll")                                                          \
    for (int mi = 0; mi < 3; ++mi) {                                           \
        int k_ = wave * 48 + mi * 16 + fr;                                     \
        af[mi] = *(const short8*)(Als + k_ * AS + lq * 16);                    \
    }                                                                          \
    int lof_ = (ch) * 32 + lq * 8;                                             \
    if (lof_ >= 360) lof_ = 0;   /* tail: A is zero there -> product 0 */      \
    _Pragma("unroll")                                                          \
    for (int ni = 0; ni < 8; ++ni) {                                           \
        int pl_ = ni >> 1;                                                     \
        int rB_ = srcT[(pp) * 4 + pl_] * 32 + (ni & 1) * 16 + fr;              \
        short8 bg = *(const short8*)(Bls + rB_ * 720 + lof_ * 2);              \
        short sg_ = (short)sgnT[(pp) * 4 + pl_];                               \
        _Pragma("unroll")                                                      \
        for (int e = 0; e < 8; ++e) bg[e] ^= sg_;                              \
        _Pragma("unroll")                                                      \
        for (int mi = 0; mi < 3; ++mi)                                         \
            acc[mi][ni] = __builtin_amdgcn_mfma_f32_16x16x32_bf16(             \
                af[mi], bg, acc[mi][ni], 0, 0, 0);                             \
    } }

    LOAD_A(0, 0);

    #pragma unroll
    for (int p = 0; p < 2; ++p) {
        #pragma unroll 1
        for (int ch = 0; ch < 12; ++ch) {
            __syncthreads();             // prior compute's LDS reads done
            WRITE_A(ch);
            __syncthreads();
            if (ch < 11)     { LOAD_A(p, ch + 1); }
            else if (p == 0) { LOAD_A(1, 0); }
            COMPUTE(p, ch);
        }
    }

#undef LOAD_A
#undef WR_E
#undef WRITE_A
#undef COMPUTE

    // store (R8-proven scalar path, unpadded interQ):
    // k = wave*48 + mi*16 + lq*4 + r ; combo c = ni*16 + fr
    #pragma unroll
    for (int mi = 0; mi < 3; ++mi) {
        int kr = wave * 48 + mi * 16 + lq * 4;
        #pragma unroll
        for (int ni = 0; ni < 8; ++ni) {
            int c = ni * 16 + fr;
            int pl = c >> 5, bc = c & 31;
            int ri = pl & 1, tt = pl >> 1;
            size_t qb = (size_t)(2 * m + ri) * MT + (size_t)(bc * 2 + tt) * NLAT;
            #pragma unroll
            for (int r = 0; r < 4; ++r) {
                int k = kr + r;
                if (k < NLAT)
                    interQ[qb + k] = __float2bfloat16(acc[mi][ni][r]);
            }
        }
    }
}

// ---------------------------------------------------------------------------
// Transpose interQ [722][23104] -> interT [23104][736] (zero K-pad)  [R8]
// ---------------------------------------------------------------------------
__global__ __launch_bounds__(256) void sht_transpose(
    const __hip_bfloat16* __restrict__ inQ, __hip_bfloat16* __restrict__ outT)
{
    __shared__ __hip_bfloat16 tile[64][65];
    const int R0 = blockIdx.x * 64;
    const int q0 = blockIdx.y * 64;
    const int tx = threadIdx.x & 63;
    const int ty = threadIdx.x >> 6;
    const __hip_bfloat16 zv = __float2bfloat16(0.f);

    for (int qq = ty; qq < 64; qq += 4) {
        int q = q0 + qq;
        tile[qq][tx] = (q < QT) ? inQ[(size_t)q * MT + R0 + tx] : zv;
    }
    __syncthreads();
    if (q0 + tx < KP) {
        for (int rr = ty; rr < 64; rr += 4) {
            outT[(size_t)(R0 + rr) * KP + q0 + tx] = tile[tx][rr];
        }
    }
}

// ---------------------------------------------------------------------------
// W table [NP=768][KP=736] bf16
// ---------------------------------------------------------------------------
__global__ __launch_bounds__(256) void sht_make_w(__hip_bfloat16* __restrict__ W)
{
    const int idx = blockIdx.x * 256 + threadIdx.x;
    const int j = idx / KP;
    const int q = idx % KP;
    float v = 0.f;
    if (j < NLON && q < QT) {
        int m = q >> 1;
        float coef = (m == 0 || m == 360) ? 1.f : 2.f;
        int ph = (m * j) % 720;
        float ang = (float)ph * (float)(2.0 * M_PI / 720.0);
        float s, c;
        __sincosf(ang, &s, &c);
        v = (q & 1) ? (-coef * s) : (coef * c);
    }
    W[idx] = __float2bfloat16(v);
}

// ---------------------------------------------------------------------------
// Stage 2 GEMM (unchanged, proven): out[R][j] = sum_q interT[R][q] * W[j][q]
// ---------------------------------------------------------------------------
__global__ __launch_bounds__(256) void sht_gemm(
    const __hip_bfloat16* __restrict__ A,   // [MT][KP]
    const __hip_bfloat16* __restrict__ W,   // [NP][KP]
    float* __restrict__ out)                // [MT][NLON]
{
    __shared__ __align__(16) __hip_bfloat16 As[BM * BK];
    __shared__ __align__(16) __hip_bfloat16 Bs[BN * BK];
    const int t  = threadIdx.x;
    const int R0 = blockIdx.x * BM;
    const int J0 = blockIdx.y * BN;

    const int rowA = t >> 2;
    const int kc   = (t & 3) * 8;
    const int gr0  = min(R0 + rowA,      MT - 1);
    const int gr1  = min(R0 + rowA + 64, MT - 1);
    const __hip_bfloat16* pa0 = A + (size_t)gr0 * KP + kc;
    const __hip_bfloat16* pa1 = A + (size_t)gr1 * KP + kc;
    const __hip_bfloat16* pb0 = W + (size_t)(J0 + rowA) * KP + kc;
    const __hip_bfloat16* pb1 = W + (size_t)(J0 + rowA + 64) * KP + kc;

    const int lane = t & 63;
    const int wave = t >> 6;
    const int wm = (wave >> 1) * 64;
    const int wn = (wave & 1) * 64;
    const int fr = lane & 15;
    const int kg = (lane >> 4) * 8;

    f32x4 acc[4][4];
    const f32x4 zero = {0.f, 0.f, 0.f, 0.f};
    #pragma unroll
    for (int i = 0; i < 4; ++i)
        #pragma unroll
        for (int j = 0; j < 4; ++j) acc[i][j] = zero;

    short8 va0 = *(const short8*)pa0;
    short8 va1 = *(const short8*)pa1;
    short8 vb0 = *(const short8*)pb0;
    short8 vb1 = *(const short8*)pb1;

    for (int kt = 0; kt < KP / BK; ++kt) {
        __syncthreads();
        *(short8*)&As[t * 8]        = va0;
        *(short8*)&As[t * 8 + 2048] = va1;
        *(short8*)&Bs[t * 8]        = vb0;
        *(short8*)&Bs[t * 8 + 2048] = vb1;
        __syncthreads();

        if (kt + 1 < KP / BK) {
            const int ko = (kt + 1) * BK;
            va0 = *(const short8*)(pa0 + ko);
            va1 = *(const short8*)(pa1 + ko);
            vb0 = *(const short8*)(pb0 + ko);
            vb1 = *(const short8*)(pb1 + ko);
        }

        short8 af[4], bg[4];
        #pragma unroll
        for (int i = 0; i < 4; ++i)
            af[i] = *(const short8*)&As[(wm + i * 16 + fr) * BK + kg];
        #pragma unroll
        for (int i = 0; i < 4; ++i)
            bg[i] = *(const short8*)&Bs[(wn + i * 16 + fr) * BK + kg];

        #pragma unroll
        for (int mi = 0; mi < 4; ++mi)
            #pragma unroll
            for (int ni = 0; ni < 4; ++ni)
                acc[mi][ni] = __builtin_amdgcn_mfma_f32_16x16x32_bf16(
                    af[mi], bg[ni], acc[mi][ni], 0, 0, 0);
    }

    const int orow = (lane >> 4) * 4;
    #pragma unroll
    for (int mi = 0; mi < 4; ++mi) {
        #pragma unroll
        for (int ni = 0; ni < 4; ++ni) {
            #pragma unroll
            for (int r = 0; r < 4; ++r) {
                int row = R0 + wm + mi * 16 + orow + r;
                int col = J0 + wn + ni * 16 + fr;
                if (row < MT && col < NLON)
                    out[(size_t)row * NLON + col] = acc[mi][ni][r];
            }
        }
    }
}

// ---------------------------------------------------------------------------
// Workspace layout (R8 proven):
//   region A [0, 34,009,088):  xT (33,269,760 B)  then interT (34,009,088 B)
//   region B [34,009,088, 67,371,264):  interQ (33,362,176 B) then W
// Liveness: xT:[prep->gemm1]  interQ:[gemm1->transpose]
//           interT:[transpose->gemm2]  W:[make_w->gemm2] (interQ dead by then)
// ---------------------------------------------------------------------------
extern "C" void kernel_launch(void* const* d_in, const int* in_sizes, int n_in,
                              void* d_out, int out_size, void* d_ws, size_t ws_size,
                              hipStream_t stream)
{
    const float* x    = (const float*)d_in[0];
    const float* dpct = (const float*)d_in[1];
    float* out        = (float*)d_out;

    char* ws = (char*)d_ws;
    __hip_bfloat16* xT     = (__hip_bfloat16*)ws;
    __hip_bfloat16* interT = (__hip_bfloat16*)ws;
    __hip_bfloat16* interQ = (__hip_bfloat16*)(ws + 34009088);
    __hip_bfloat16* Wt     = (__hip_bfloat16*)(ws + 34009088);

    dim3 gp(12, 6, 64);
    sht_prep_x<<<gp, 256, 0, stream>>>(x, xT);

    sht_gemm1<<<MMAX, 512, 0, stream>>>(dpct, xT, interQ);

    dim3 gt(MT / 64, 12);
    sht_transpose<<<gt, 256, 0, stream>>>(interQ, interT);

    sht_make_w<<<(NP * KP) / 256, 256, 0, stream>>>(Wt);

    dim3 gg((MT + BM - 1) / BM, NP / BN);
    sht_gemm<<<gg, 256, 0, stream>>>(interT, Wt, out);
}